// Round 2
// baseline (330.392 us; speedup 1.0000x reference)
//
#include <hip/hip_runtime.h>
#include <hip/hip_cooperative_groups.h>
#include <math.h>

// EquiTritonModel: N=10000 nodes, E=160000 edges, D=32, H=16, NB=16.
// R15 -> R16: per-iteration total (161us) was ~3x the dominant kernel
// (47us) with no other kernel >46us => ~90-100us of inter-kernel
// launch/gap overhead across 4 sequential dispatches. Fused everything
// into ONE cooperative kernel with grid.sync() phase boundaries:
//   phase0: TI/G tables + zero zacc + zero out
//   phase1: edges -> fire-and-forget fp32 atomics into zacc (ONLY write)
//   phase2: nodes -> QP table + readout term (register accumulator)
//   phase3: edges (recompute geometry + h1 recurrence; QP gathers)
// hbuf/ubuf eliminated (phase3 recomputes from L2-resident ei/coords).
// Grid sized via occupancy API so cooperative co-residency holds.

namespace cg = cooperative_groups;

namespace {
constexpr int   NATOMS   = 100;
constexpr float PI_F     = 3.14159265358979323846f;
constexpr float INV4PI_F = 0.28209479177387814f;   // 1/sqrt(4*pi)
constexpr float SQRT3_F  = 1.7320508075688772f;
constexpr float CUT_F    = 6.0f;
constexpr float BASIS_C  = 2.3094010767585034f;    // sqrt(2/6)*sqrt(16)
constexpr float N0_F     = 0.17677669529663687f;   // 1/sqrt(32)
constexpr float K0_F = INV4PI_F * N0_F * 0.0625f;  // z0 scale incl /DEG
constexpr float K1_F = SQRT3_F * INV4PI_F * N0_F * 0.0625f;
constexpr float P2SC = INV4PI_F * N0_F * (1.0f / 64.0f);
}

__device__ __forceinline__ float silu_fast(float x) {
  return x / (1.0f + __expf(-x));
}

__device__ __forceinline__ float block_reduce_sum(float v) {
  #pragma unroll
  for (int o = 32; o > 0; o >>= 1) v += __shfl_down(v, o, 64);
  __shared__ float ls[8];
  int lane = threadIdx.x & 63;
  int w    = threadIdx.x >> 6;
  if (lane == 0) ls[w] = v;
  __syncthreads();
  float s = 0.f;
  if (threadIdx.x == 0) {
    int nw = (blockDim.x + 63) >> 6;
    for (int i = 0; i < nw; ++i) s += ls[i];
  }
  return s;
}

__global__ void __launch_bounds__(256)
fused_kernel(const int* __restrict__ an,
             const float* __restrict__ coords,
             const int* __restrict__ ei,
             const float* __restrict__ atom_emb,
             const float* __restrict__ fc0_w1,
             const float* __restrict__ fc0_w2,
             const float* __restrict__ fc1_w1,
             const float* __restrict__ fc1_w2,
             const float* __restrict__ w_readout,
             float* __restrict__ TI,
             float* __restrict__ G1T,
             float* __restrict__ G4T,
             float* __restrict__ zacc,
             float* __restrict__ QP,
             float* __restrict__ out,
             int N, int E) {
  cg::grid_group grid = cg::this_grid();
  const int tt     = threadIdx.x;
  const int lane   = tt & 63;
  const int t      = tt & 15;
  const int base   = lane & 48;
  const int ggid   = blockIdx.x * 16 + (tt >> 4);
  const int ngroups = gridDim.x * 16;
  const float angc = PI_F / CUT_F;

  // ---------------- phase 0: tables + zeroing ----------------
  {
    float4* z4 = (float4*)zacc;
    int n4 = N * 16;
    for (int i = blockIdx.x * 256 + tt; i < n4; i += gridDim.x * 256)
      z4[i] = make_float4(0.f, 0.f, 0.f, 0.f);
    if (blockIdx.x == 0 && tt == 0) *out = 0.f;

    for (int task = ggid; task < NATOMS * 16 + 16; task += ngroups) {
      if (task < NATOMS * 16) {
        int b = task >> 4, j = task & 15;
        float s0 = 0.f, s1 = 0.f;
        #pragma unroll
        for (int d = 0; d < 32; ++d) {
          float x = atom_emb[b * 32 + d];
          s0 = fmaf(x, fc0_w2[j * 1024 + d * 16 + t], s0);
          s1 = fmaf(x, fc0_w2[j * 1024 + 512 + d * 16 + t], s1);
        }
        TI[b * 512 + j * 32 + 2 * t]     = s0;
        TI[b * 512 + j * 32 + 2 * t + 1] = s1;
      } else {
        int j = task - NATOMS * 16;
        float g1 = 0.f, g4 = 0.f;
        #pragma unroll
        for (int k = 0; k < 16; ++k) {
          float r = w_readout[k];
          g1 = fmaf(fc1_w2[j * 1024 + t * 16 + k], r, g1);
          g4 = fmaf(fc1_w2[j * 1024 + 768 + t * 16 + k], r, g4);
        }
        G1T[t * 16 + j] = g1;
        G4T[t * 16 + j] = g4;
      }
    }
  }
  grid.sync();

  // ---------------- phase 1: edges -> zacc atomics ----------------
  {
    float w0c[16];
    #pragma unroll
    for (int k = 0; k < 16; ++k) w0c[k] = fc0_w1[k * 16 + t];

    for (int e0 = ggid; e0 < E; e0 += 2 * ngroups) {
      int eA = e0;
      int eB = e0 + ngroups;
      bool vB = eB < E;
      int eBc = vB ? eB : eA;

      int sA = ei[eA],  dA = ei[E + eA];
      int sB = ei[eBc], dB = ei[E + eBc];
      float sxA = coords[3 * sA + 0], syA = coords[3 * sA + 1], szA = coords[3 * sA + 2];
      float dxA = coords[3 * dA + 0], dyA = coords[3 * dA + 1], dzA = coords[3 * dA + 2];
      float sxB = coords[3 * sB + 0], syB = coords[3 * sB + 1], szB = coords[3 * sB + 2];
      float dxB = coords[3 * dB + 0], dyB = coords[3 * dB + 1], dzB = coords[3 * dB + 2];
      int aA = an[sA], aB = an[sB];

      float vxA = sxA - dxA, vyA = syA - dyA, vzA = szA - dzA;
      float vxB = sxB - dxB, vyB = syB - dyB, vzB = szB - dzB;
      float distA = sqrtf(vxA * vxA + vyA * vyA + vzA * vzA);
      float distB = sqrtf(vxB * vxB + vyB * vyB + vzB * vzB);
      float ivA = 1.0f / fmaxf(distA, 1e-9f);
      float ivB = 1.0f / fmaxf(distB, 1e-9f);
      float uxA = vxA * ivA, uyA = vyA * ivA, uzA = vzA * ivA;
      float uxB = vxB * ivB, uyB = vyB * ivB, uzB = vzB * ivB;
      float bcA = (distA < CUT_F) ? (BASIS_C * ivA) : 0.0f;
      float bcB = (distB < CUT_F) ? (BASIS_C * ivB) : 0.0f;

      float angA = angc * distA, angB = angc * distB;
      float scA = __sinf(angA), twA = 2.0f * __cosf(angA), spA = 0.f;
      float scB = __sinf(angB), twB = 2.0f * __cosf(angB), spB = 0.f;
      float a0A = 0.f, a0B = 0.f;
      #pragma unroll
      for (int k = 0; k < 16; ++k) {
        a0A = fmaf(scA, w0c[k], a0A);
        a0B = fmaf(scB, w0c[k], a0B);
        float snA = fmaf(twA, scA, -spA); spA = scA; scA = snA;
        float snB = fmaf(twB, scB, -spB); spB = scB; scB = snB;
      }
      float h0A = silu_fast(a0A * bcA * 0.25f);
      float h0B = silu_fast(a0B * bcB * 0.25f);

      const float2* tpA = (const float2*)(TI + aA * 512) + t;
      const float2* tpB = (const float2*)(TI + aB * 512) + t;
      float u0A = 0.f, u1A = 0.f, u0B = 0.f, u1B = 0.f;
      #pragma unroll
      for (int j = 0; j < 16; ++j) {
        float hjA = __shfl(h0A, base + j, 64);
        float hjB = __shfl(h0B, base + j, 64);
        float2 TA = tpA[j * 16];
        float2 TB = tpB[j * 16];
        u0A = fmaf(hjA, TA.x, u0A);
        u1A = fmaf(hjA, TA.y, u1A);
        u0B = fmaf(hjB, TB.x, u0B);
        u1B = fmaf(hjB, TB.y, u1B);
      }

      {
        float* za = zacc + (size_t)dA * 64 + t;
        float m1 = K1_F * u1A;
        unsafeAtomicAdd(za,      K0_F * u0A);
        unsafeAtomicAdd(za + 16, m1 * uxA);
        unsafeAtomicAdd(za + 32, m1 * uyA);
        unsafeAtomicAdd(za + 48, m1 * uzA);
      }
      if (vB) {
        float* zb = zacc + (size_t)dB * 64 + t;
        float m1 = K1_F * u1B;
        unsafeAtomicAdd(zb,      K0_F * u0B);
        unsafeAtomicAdd(zb + 16, m1 * uxB);
        unsafeAtomicAdd(zb + 32, m1 * uyB);
        unsafeAtomicAdd(zb + 48, m1 * uzB);
      }
    }
  }
  grid.sync();

  // ---------------- phase 2: nodes -> QP + readout ----------------
  __shared__ float ggs[512];          // [0:256)=G1T, [256:512)=G4T
  ggs[tt]       = G1T[tt];
  ggs[256 + tt] = G4T[tt];
  __syncthreads();

  float rsum = 0.f;
  {
    float rr = w_readout[t];
    for (int n = ggid; n < N; n += ngroups) {
      size_t nb = (size_t)n * 64;
      float z0 = zacc[nb + t];
      float zx = zacc[nb + 16 + t];
      float zy = zacc[nb + 32 + t];
      float zz = zacc[nb + 48 + t];

      float Q = 0.f, Px = 0.f, Py = 0.f, Pz = 0.f;
      #pragma unroll
      for (int h = 0; h < 16; ++h) {
        float z0h = __shfl(z0, base + h, 64);
        float zxh = __shfl(zx, base + h, 64);
        float zyh = __shfl(zy, base + h, 64);
        float zzh = __shfl(zz, base + h, 64);
        float g1 = ggs[h * 16 + t];
        float g4 = ggs[256 + h * 16 + t];
        Q  = fmaf(g1, z0h, Q);
        Px = fmaf(g4, zxh, Px);
        Py = fmaf(g4, zyh, Py);
        Pz = fmaf(g4, zzh, Pz);
      }
      QP[nb + t]      = Q;
      QP[nb + 16 + t] = Px;
      QP[nb + 32 + t] = Py;
      QP[nb + 48 + t] = Pz;
      rsum = fmaf(0.25f * z0, rr, rsum);
    }
  }
  grid.sync();

  // ---------------- phase 3: edges (recompute) + QP gather ----------------
  float c3 = 0.f;
  {
    float w1c[16];
    #pragma unroll
    for (int k = 0; k < 16; ++k) w1c[k] = fc1_w1[k * 16 + t];

    for (int e0 = ggid; e0 < E; e0 += 2 * ngroups) {
      int eA = e0;
      int eB = e0 + ngroups;
      bool vB = eB < E;
      int eBc = vB ? eB : eA;

      int sA = ei[eA],  dA = ei[E + eA];
      int sB = ei[eBc], dB = ei[E + eBc];
      float sxA = coords[3 * sA + 0], syA = coords[3 * sA + 1], szA = coords[3 * sA + 2];
      float dxA = coords[3 * dA + 0], dyA = coords[3 * dA + 1], dzA = coords[3 * dA + 2];
      float sxB = coords[3 * sB + 0], syB = coords[3 * sB + 1], szB = coords[3 * sB + 2];
      float dxB = coords[3 * dB + 0], dyB = coords[3 * dB + 1], dzB = coords[3 * dB + 2];

      float vxA = sxA - dxA, vyA = syA - dyA, vzA = szA - dzA;
      float vxB = sxB - dxB, vyB = syB - dyB, vzB = szB - dzB;
      float distA = sqrtf(vxA * vxA + vyA * vyA + vzA * vzA);
      float distB = sqrtf(vxB * vxB + vyB * vyB + vzB * vzB);
      float ivA = 1.0f / fmaxf(distA, 1e-9f);
      float ivB = 1.0f / fmaxf(distB, 1e-9f);
      float uxA = vxA * ivA, uyA = vyA * ivA, uzA = vzA * ivA;
      float uxB = vxB * ivB, uyB = vyB * ivB, uzB = vzB * ivB;
      float bcA = (distA < CUT_F) ? (BASIS_C * ivA) : 0.0f;
      float bcB = (distB < CUT_F) ? (BASIS_C * ivB) : 0.0f;

      float angA = angc * distA, angB = angc * distB;
      float scA = __sinf(angA), twA = 2.0f * __cosf(angA), spA = 0.f;
      float scB = __sinf(angB), twB = 2.0f * __cosf(angB), spB = 0.f;
      float a1A = 0.f, a1B = 0.f;
      #pragma unroll
      for (int k = 0; k < 16; ++k) {
        a1A = fmaf(scA, w1c[k], a1A);
        a1B = fmaf(scB, w1c[k], a1B);
        float snA = fmaf(twA, scA, -spA); spA = scA; scA = snA;
        float snB = fmaf(twB, scB, -spB); spB = scB; scB = snB;
      }
      float h1A = silu_fast(a1A * bcA * 0.25f);
      float h1B = silu_fast(a1B * bcB * 0.25f);

      {
        size_t qa = (size_t)sA * 64;
        float Qt  = QP[qa + t];
        float Pxt = QP[qa + 16 + t];
        float Pyt = QP[qa + 32 + t];
        float Pzt = QP[qa + 48 + t];
        c3 = fmaf(h1A, fmaf(Pxt, uxA, fmaf(Pyt, uyA, fmaf(Pzt, uzA, Qt))), c3);
      }
      if (vB) {
        size_t qb = (size_t)sB * 64;
        float Qt  = QP[qb + t];
        float Pxt = QP[qb + 16 + t];
        float Pyt = QP[qb + 32 + t];
        float Pzt = QP[qb + 48 + t];
        c3 = fmaf(h1B, fmaf(Pxt, uxB, fmaf(Pyt, uyB, fmaf(Pzt, uzB, Qt))), c3);
      }
    }
  }

  float csum = fmaf(P2SC, c3, rsum);
  float tot = block_reduce_sum(csum);
  if (tt == 0) atomicAdd(out, tot);
}

extern "C" void kernel_launch(void* const* d_in, const int* in_sizes, int n_in,
                              void* d_out, int out_size, void* d_ws, size_t ws_size,
                              hipStream_t stream) {
  const int*   an        = (const int*)d_in[0];
  const float* coords    = (const float*)d_in[1];
  const int*   ei        = (const int*)d_in[2];
  const float* atom_emb  = (const float*)d_in[3];
  const float* fc0_w1    = (const float*)d_in[4];
  const float* fc0_w2    = (const float*)d_in[5];
  const float* fc1_w1    = (const float*)d_in[6];
  const float* fc1_w2    = (const float*)d_in[7];
  const float* w_readout = (const float*)d_in[8];

  int N = in_sizes[0];
  int E = in_sizes[2] / 2;

  // ws layout (16B-aligned first)
  float* zacc = (float*)d_ws;                   // N*64   (2.6 MB)
  float* QP   = zacc + (size_t)N * 64;          // N*64   (2.6 MB)
  float* TI   = QP + (size_t)N * 64;            // 100*512
  float* G1T  = TI + NATOMS * 512;              // 256
  float* G4T  = G1T + 256;                      // 256
  float* out  = (float*)d_out;

  // Grid sized for guaranteed cooperative co-residency (queried once).
  static int coop_grid = 0;
  if (coop_grid == 0) {
    int mb = 0;
    hipOccupancyMaxActiveBlocksPerMultiprocessor(&mb, fused_kernel, 256, 0);
    if (mb < 1) mb = 1;
    int dev = 0;
    hipGetDevice(&dev);
    hipDeviceProp_t prop;
    hipGetDeviceProperties(&prop, dev);
    int cus = prop.multiProcessorCount > 0 ? prop.multiProcessorCount : 256;
    coop_grid = mb * cus;
    if (coop_grid > 2048) coop_grid = 2048;
  }

  void* args[] = {
    (void*)&an, (void*)&coords, (void*)&ei, (void*)&atom_emb,
    (void*)&fc0_w1, (void*)&fc0_w2, (void*)&fc1_w1, (void*)&fc1_w2,
    (void*)&w_readout, (void*)&TI, (void*)&G1T, (void*)&G4T,
    (void*)&zacc, (void*)&QP, (void*)&out, (void*)&N, (void*)&E
  };
  hipLaunchCooperativeKernel((void*)fused_kernel, dim3(coop_grid), dim3(256),
                             args, 0, stream);
}

// Round 3
// 151.515 us; speedup vs baseline: 2.1806x; 2.1806x over previous
//
#include <hip/hip_runtime.h>
#include <math.h>

// EquiTritonModel: N=10000 nodes, E=160000 edges, D=32, H=16, NB=16.
// R16 -> R17: cooperative grid.sync() measured ~100us each (fused kernel
// 400us, VALUBusy 4.8%) => kernel boundaries (~15us) are the cheap
// barrier on gfx950. Back to separate dispatches, but restructured from
// 4 kernels / 2 edge sweeps to 3 kernels / 1 edge sweep:
//   K1 table_kernel: TI table + zero zacc/sacc + zero out
//   K2 edge_kernel : per-edge everything; 8 fire-and-forget fp32 atomics
//                    zacc[dst] += {K0*u0, K1*u1*u}   (z-aggregation)
//                    sacc[src] += {h1, h1*u}         (NEW: regrouped
//                    phase-2 sum by source => edge sweep #2 eliminated)
//   K3 node_kernel : G-tables in LDS (computed in-kernel), per-node
//                    Q/P transform, c = Q.A + P.B (+ readout), reduce.
// hbuf/ubuf (13 MB round trip) and edge2 deleted.

namespace {
constexpr int   NATOMS   = 100;
constexpr float PI_F     = 3.14159265358979323846f;
constexpr float INV4PI_F = 0.28209479177387814f;   // 1/sqrt(4*pi)
constexpr float SQRT3_F  = 1.7320508075688772f;
constexpr float CUT_F    = 6.0f;
constexpr float BASIS_C  = 2.3094010767585034f;    // sqrt(2/6)*sqrt(16)
constexpr float N0_F     = 0.17677669529663687f;   // 1/sqrt(32)
constexpr float K0_F = INV4PI_F * N0_F * 0.0625f;  // z0 scale incl /DEG
constexpr float K1_F = SQRT3_F * INV4PI_F * N0_F * 0.0625f;
constexpr float P2SC = INV4PI_F * N0_F * (1.0f / 64.0f);
}

__device__ __forceinline__ float silu_fast(float x) {
  return x / (1.0f + __expf(-x));
}

__device__ __forceinline__ float block_reduce_sum(float v) {
  #pragma unroll
  for (int o = 32; o > 0; o >>= 1) v += __shfl_down(v, o, 64);
  __shared__ float ls[8];
  int lane = threadIdx.x & 63;
  int w    = threadIdx.x >> 6;
  if (lane == 0) ls[w] = v;
  __syncthreads();
  float s = 0.f;
  if (threadIdx.x == 0) {
    int nw = (blockDim.x + 63) >> 6;
    for (int i = 0; i < nw; ++i) s += ls[i];
  }
  return s;
}

// ---------------------------------------------------------------------------
// table_kernel: blocks [0,NATOMS) -> TI tables; blocks >= NATOMS zero
// zacc+sacc (N*128 floats, viewed as float4) — no hipMemset needed.
// ---------------------------------------------------------------------------
__global__ void __launch_bounds__(256)
table_kernel(const float* __restrict__ atom_emb,
             const float* __restrict__ fc0_w2,
             float* __restrict__ TI,
             float4* __restrict__ zero4,   // zacc||sacc as float4
             float* __restrict__ out,
             int NZ4) {
  int b = blockIdx.x;
  int tt = threadIdx.x;
  if (b < NATOMS) {
    int j = tt >> 4;
    int h = tt & 15;
    float s0 = 0.f, s1 = 0.f;
    #pragma unroll
    for (int d = 0; d < 32; ++d) {
      float x = atom_emb[b * 32 + d];
      s0 = fmaf(x, fc0_w2[j * 1024 + d * 16 + h], s0);
      s1 = fmaf(x, fc0_w2[j * 1024 + 512 + d * 16 + h], s1);
    }
    TI[b * 512 + j * 32 + 2 * h]     = s0;
    TI[b * 512 + j * 32 + 2 * h + 1] = s1;
    if (b == 0 && tt == 0) *out = 0.f;
  } else {
    int idx = (b - NATOMS) * 256 + tt;
    if (idx < NZ4) zero4[idx] = make_float4(0.f, 0.f, 0.f, 0.f);
  }
}

// ---------------------------------------------------------------------------
// edge_kernel: 16 groups x 16 lanes; group g handles edges b*32+g and
// b*32+16+g (2-edge ILP pipeline). Single sweep; all outputs are
// fire-and-forget fp32 atomics (no return => no dependency stall):
//   zacc[dst*64 + {t,16+t,32+t,48+t}] += {K0*u0, K1*u1*ux/uy/uz}
//   sacc[src*64 + {t,16+t,32+t,48+t}] += {h1,    h1*ux/uy/uz}
// ---------------------------------------------------------------------------
__global__ void __launch_bounds__(256)
edge_kernel(const int* __restrict__ ei,
            const float* __restrict__ coords,
            const int* __restrict__ an,
            const float* __restrict__ TI,
            const float* __restrict__ fc0_w1,
            const float* __restrict__ fc1_w1,
            float* __restrict__ zacc,
            float* __restrict__ sacc,
            int E) {
  int lane = threadIdx.x & 63;
  int g    = threadIdx.x >> 4;       // block group 0..15
  int t    = threadIdx.x & 15;
  int base = lane & 48;

  float w0c[16], w1c[16];
  #pragma unroll
  for (int k = 0; k < 16; ++k) {
    w0c[k] = fc0_w1[k * 16 + t];
    w1c[k] = fc1_w1[k * 16 + t];
  }

  const float angc = PI_F / CUT_F;
  int eA = blockIdx.x * 32 + g;
  int eB = eA + 16;
  bool vA = eA < E, vB = eB < E;
  int eAc = vA ? eA : 0, eBc = vB ? eB : 0;

  // ---- phase 1: all input loads ----
  int sA = ei[eAc], dA = ei[E + eAc];
  int sB = ei[eBc], dB = ei[E + eBc];
  float sxA = coords[3 * sA + 0], syA = coords[3 * sA + 1], szA = coords[3 * sA + 2];
  float dxA = coords[3 * dA + 0], dyA = coords[3 * dA + 1], dzA = coords[3 * dA + 2];
  float sxB = coords[3 * sB + 0], syB = coords[3 * sB + 1], szB = coords[3 * sB + 2];
  float dxB = coords[3 * dB + 0], dyB = coords[3 * dB + 1], dzB = coords[3 * dB + 2];
  int aA = an[sA], aB = an[sB];

  // ---- phase 2: geometry ----
  float vxA = sxA - dxA, vyA = syA - dyA, vzA = szA - dzA;
  float vxB = sxB - dxB, vyB = syB - dyB, vzB = szB - dzB;
  float distA = sqrtf(vxA * vxA + vyA * vyA + vzA * vzA);
  float distB = sqrtf(vxB * vxB + vyB * vyB + vzB * vzB);
  float ivA = 1.0f / fmaxf(distA, 1e-9f);
  float ivB = 1.0f / fmaxf(distB, 1e-9f);
  float uxA = vxA * ivA, uyA = vyA * ivA, uzA = vzA * ivA;
  float uxB = vxB * ivB, uyB = vyB * ivB, uzB = vzB * ivB;
  float bcA = (distA < CUT_F) ? (BASIS_C * ivA) : 0.0f;
  float bcB = (distB < CUT_F) ? (BASIS_C * ivB) : 0.0f;

  // ---- phase 3: interleaved sine recurrences (shared sines for h0/h1) ----
  float angA = angc * distA, angB = angc * distB;
  float scA = __sinf(angA), twA = 2.0f * __cosf(angA), spA = 0.f;
  float scB = __sinf(angB), twB = 2.0f * __cosf(angB), spB = 0.f;
  float a0A = 0.f, a1A = 0.f, a0B = 0.f, a1B = 0.f;
  #pragma unroll
  for (int k = 0; k < 16; ++k) {
    a0A = fmaf(scA, w0c[k], a0A);
    a1A = fmaf(scA, w1c[k], a1A);
    a0B = fmaf(scB, w0c[k], a0B);
    a1B = fmaf(scB, w1c[k], a1B);
    float snA = fmaf(twA, scA, -spA); spA = scA; scA = snA;
    float snB = fmaf(twB, scB, -spB); spB = scB; scB = snB;
  }
  float h0A = silu_fast(a0A * bcA * 0.25f);
  float h1A = silu_fast(a1A * bcA * 0.25f);
  float h0B = silu_fast(a0B * bcB * 0.25f);
  float h1B = silu_fast(a1B * bcB * 0.25f);

  // sacc atomics go out as early as possible (h1 ready before TI loop)
  if (vA) {
    float* sa = sacc + (size_t)sA * 64 + t;
    unsafeAtomicAdd(sa,      h1A);
    unsafeAtomicAdd(sa + 16, h1A * uxA);
    unsafeAtomicAdd(sa + 32, h1A * uyA);
    unsafeAtomicAdd(sa + 48, h1A * uzA);
  }
  if (vB) {
    float* sb = sacc + (size_t)sB * 64 + t;
    unsafeAtomicAdd(sb,      h1B);
    unsafeAtomicAdd(sb + 16, h1B * uxB);
    unsafeAtomicAdd(sb + 32, h1B * uyB);
    unsafeAtomicAdd(sb + 48, h1B * uzB);
  }

  // ---- phase 4: interleaved TI loads + contraction ----
  const float2* tpA = (const float2*)(TI + aA * 512) + t;
  const float2* tpB = (const float2*)(TI + aB * 512) + t;
  float u0A = 0.f, u1A = 0.f, u0B = 0.f, u1B = 0.f;
  #pragma unroll
  for (int j = 0; j < 16; ++j) {
    float hjA = __shfl(h0A, base + j, 64);
    float hjB = __shfl(h0B, base + j, 64);
    float2 TA = tpA[j * 16];
    float2 TB = tpB[j * 16];
    u0A = fmaf(hjA, TA.x, u0A);
    u1A = fmaf(hjA, TA.y, u1A);
    u0B = fmaf(hjB, TB.x, u0B);
    u1B = fmaf(hjB, TB.y, u1B);
  }

  // ---- phase 5: z-side atomics ----
  if (vA) {
    float* za = zacc + (size_t)dA * 64 + t;
    float m1 = K1_F * u1A;
    unsafeAtomicAdd(za,      K0_F * u0A);
    unsafeAtomicAdd(za + 16, m1 * uxA);
    unsafeAtomicAdd(za + 32, m1 * uyA);
    unsafeAtomicAdd(za + 48, m1 * uzA);
  }
  if (vB) {
    float* zb = zacc + (size_t)dB * 64 + t;
    float m1 = K1_F * u1B;
    unsafeAtomicAdd(zb,      K0_F * u0B);
    unsafeAtomicAdd(zb + 16, m1 * uxB);
    unsafeAtomicAdd(zb + 32, m1 * uyB);
    unsafeAtomicAdd(zb + 48, m1 * uzB);
  }
}

// ---------------------------------------------------------------------------
// node_kernel: 16 nodes/block. Computes G1T/G4T into LDS (16 FMA per
// thread — no precomputed table needed), then per node: Q/P transform of
// zacc via shuffles, dot against sacc (A,B), plus readout term.
// ---------------------------------------------------------------------------
__global__ void __launch_bounds__(256)
node_kernel(const float* __restrict__ zacc,
            const float* __restrict__ sacc,
            const float* __restrict__ fc1_w2,
            const float* __restrict__ w_readout,
            float* __restrict__ out,
            int N) {
  __shared__ float ggs[512];          // [0:256)=G1T, [256:512)=G4T
  {
    int j = threadIdx.x >> 4;         // hidden index of fc1_w2 row
    int h = threadIdx.x & 15;
    float g1 = 0.f, g4 = 0.f;
    #pragma unroll
    for (int k = 0; k < 16; ++k) {
      float r = w_readout[k];
      g1 = fmaf(fc1_w2[j * 1024 + h * 16 + k], r, g1);
      g4 = fmaf(fc1_w2[j * 1024 + 768 + h * 16 + k], r, g4);
    }
    ggs[h * 16 + j]       = g1;
    ggs[256 + h * 16 + j] = g4;
  }
  __syncthreads();

  int lane = threadIdx.x & 63;
  int t    = lane & 15;
  int base = lane & 48;
  int node = blockIdx.x * 16 + (threadIdx.x >> 4);
  bool valid = node < N;
  size_t nb = (size_t)(valid ? node : 0) * 64;

  float z0 = zacc[nb + t];
  float zx = zacc[nb + 16 + t];
  float zy = zacc[nb + 32 + t];
  float zz = zacc[nb + 48 + t];
  float A  = sacc[nb + t];
  float Bx = sacc[nb + 16 + t];
  float By = sacc[nb + 32 + t];
  float Bz = sacc[nb + 48 + t];

  float Q = 0.f, Px = 0.f, Py = 0.f, Pz = 0.f;
  #pragma unroll
  for (int h = 0; h < 16; ++h) {
    float z0h = __shfl(z0, base + h, 64);
    float zxh = __shfl(zx, base + h, 64);
    float zyh = __shfl(zy, base + h, 64);
    float zzh = __shfl(zz, base + h, 64);
    float g1 = ggs[h * 16 + t];
    float g4 = ggs[256 + h * 16 + t];
    Q  = fmaf(g1, z0h, Q);
    Px = fmaf(g4, zxh, Px);
    Py = fmaf(g4, zyh, Py);
    Pz = fmaf(g4, zzh, Pz);
  }

  float c = 0.f;
  if (valid) {
    float dotp = fmaf(Q, A, fmaf(Px, Bx, fmaf(Py, By, Pz * Bz)));
    c = fmaf(0.25f * z0, w_readout[t], P2SC * dotp);
  }

  float tot = block_reduce_sum(c);
  if (threadIdx.x == 0) atomicAdd(out, tot);
}

extern "C" void kernel_launch(void* const* d_in, const int* in_sizes, int n_in,
                              void* d_out, int out_size, void* d_ws, size_t ws_size,
                              hipStream_t stream) {
  const int*   an        = (const int*)d_in[0];
  const float* coords    = (const float*)d_in[1];
  const int*   ei        = (const int*)d_in[2];
  const float* atom_emb  = (const float*)d_in[3];
  const float* fc0_w1    = (const float*)d_in[4];
  const float* fc0_w2    = (const float*)d_in[5];
  const float* fc1_w1    = (const float*)d_in[6];
  const float* fc1_w2    = (const float*)d_in[7];
  const float* w_readout = (const float*)d_in[8];

  int N = in_sizes[0];
  int E = in_sizes[2] / 2;

  // ws layout (16B-aligned): zacc and sacc contiguous so one zero pass
  // covers both.
  float* zacc = (float*)d_ws;                   // N*64   (2.6 MB)
  float* sacc = zacc + (size_t)N * 64;          // N*64   (2.6 MB)
  float* TI   = sacc + (size_t)N * 64;          // 100*512
  float* out  = (float*)d_out;

  int NZ4 = N * 32;                             // (zacc+sacc) as float4
  int zblocks = (NZ4 + 255) / 256;
  table_kernel<<<NATOMS + zblocks, 256, 0, stream>>>(
      atom_emb, fc0_w2, TI, (float4*)zacc, out, NZ4);

  edge_kernel<<<(E + 31) / 32, 256, 0, stream>>>(
      ei, coords, an, TI, fc0_w1, fc1_w1, zacc, sacc, E);

  node_kernel<<<(N + 15) / 16, 256, 0, stream>>>(
      zacc, sacc, fc1_w2, w_readout, out, N);
}